// Round 1
// baseline (422.998 us; speedup 1.0000x reference)
//
#include <hip/hip_runtime.h>
#include <hip/hip_bf16.h>

namespace {
constexpr int kN    = 8192;   // nodes
constexpr int kFin  = 512;
constexpr int kFout = 64;
constexpr float kAlpha = 0.2f;

using bf16x8 = __attribute__((ext_vector_type(8))) short;
using f32x4  = __attribute__((ext_vector_type(4))) float;

__device__ __forceinline__ unsigned short f2bf(float x) {
  return __builtin_bit_cast(unsigned short, __float2bfloat16(x));
}
} // namespace

// ---------------------------------------------------------------------------
// Kernel 1: h = X @ W (fp32); s_src = h@a_src; s_dst = h@a_dst;
// hT (bf16 bits, [64][8192]) for the MFMA B-operand of kernel 3.
// grid 512 x 256 thr: block = 16 rows, wave = 4 rows, lane = feature.
// ---------------------------------------------------------------------------
__global__ __launch_bounds__(256) void k_linear(
    const float* __restrict__ X, const float* __restrict__ W, const float* __restrict__ A,
    unsigned short* __restrict__ hT, float* __restrict__ s_src, float* __restrict__ s_dst)
{
  const int t = threadIdx.x;
  const int wv = t >> 6, lane = t & 63;
  const int i0 = blockIdx.x * 16;
  const int r0 = i0 + wv * 4;
  float acc0 = 0.f, acc1 = 0.f, acc2 = 0.f, acc3 = 0.f;
  const float* x0 = X + (size_t)r0 * kFin;
  for (int k = 0; k < kFin; k += 4) {
    const float4 xa = *(const float4*)(x0 + k);
    const float4 xb = *(const float4*)(x0 + kFin + k);
    const float4 xc = *(const float4*)(x0 + 2 * kFin + k);
    const float4 xd = *(const float4*)(x0 + 3 * kFin + k);
#pragma unroll
    for (int j = 0; j < 4; ++j) {
      const float wk = W[(k + j) * kFout + lane];   // coalesced 256B/wave
      acc0 = fmaf(((const float*)&xa)[j], wk, acc0);
      acc1 = fmaf(((const float*)&xb)[j], wk, acc1);
      acc2 = fmaf(((const float*)&xc)[j], wk, acc2);
      acc3 = fmaf(((const float*)&xd)[j], wk, acc3);
    }
  }
  const float asrc = A[lane], adst = A[kFout + lane];
  float accs[4] = {acc0, acc1, acc2, acc3};
#pragma unroll
  for (int r = 0; r < 4; ++r) {
    float vs = accs[r] * asrc;
    float vd = accs[r] * adst;
#pragma unroll
    for (int off = 32; off > 0; off >>= 1) {
      vs += __shfl_xor(vs, off, 64);
      vd += __shfl_xor(vd, off, 64);
    }
    if (lane == 0) { s_src[r0 + r] = vs; s_dst[r0 + r] = vd; }
  }
  // transpose h (bf16) through LDS so hT global stores are 8B contiguous
  __shared__ unsigned short h_sm[16][64];
#pragma unroll
  for (int r = 0; r < 4; ++r) h_sm[wv * 4 + r][lane] = f2bf(accs[r]);
  __syncthreads();
  const int f = t >> 2, io = (t & 3) * 4;
  const unsigned int u0 = (unsigned int)h_sm[io + 0][f] | ((unsigned int)h_sm[io + 1][f] << 16);
  const unsigned int u1 = (unsigned int)h_sm[io + 2][f] | ((unsigned int)h_sm[io + 3][f] << 16);
  *(uint2*)(hT + (size_t)f * kN + i0 + io) = make_uint2(u0, u1);
}

// ---------------------------------------------------------------------------
// Kernel 2: S = max_j s_dst[j]  (single block)
// ---------------------------------------------------------------------------
__global__ __launch_bounds__(1024) void k_smax(const float* __restrict__ s_dst,
                                               float* __restrict__ Sout)
{
  __shared__ float red[16];
  float m = -3.4e38f;
  for (int i = threadIdx.x; i < kN; i += 1024) m = fmaxf(m, s_dst[i]);
#pragma unroll
  for (int off = 32; off > 0; off >>= 1) m = fmaxf(m, __shfl_xor(m, off, 64));
  if ((threadIdx.x & 63) == 0) red[threadIdx.x >> 6] = m;
  __syncthreads();
  if (threadIdx.x == 0) {
    float s = red[0];
#pragma unroll
    for (int i = 1; i < 16; ++i) s = fmaxf(s, red[i]);
    *Sout = s;
  }
}

// ---------------------------------------------------------------------------
// Kernel 3: fused mask + softmax + (attention @ h) + elu.
// grid 512 (BI=16 rows/block), 256 thr (4 waves). Chunk BJ=128 over j.
// P-tile (16x128 bf16) computed by VALU straight into MFMA-A layout;
// hT-tile (64x128 bf16, L2-resident) staged to LDS; 4 waves x 4 MFMA/chunk.
// Softmax shift m_i = lrelu(s_src[i] + max_j s_dst[j]) >= row max -> no
// online rescaling needed; l accumulated in fp32 registers.
// ---------------------------------------------------------------------------
__global__ __launch_bounds__(256) void k_attn(
    const int* __restrict__ adj, const unsigned short* __restrict__ hTg,
    const float* __restrict__ s_src, const float* __restrict__ s_dst,
    const float* __restrict__ Sp, float* __restrict__ out)
{
  const int t = threadIdx.x;
  const int wv = t >> 6, lane = t & 63;
  const int i0 = blockIdx.x * 16;
  const int pr = t >> 4, jb = t & 15;   // p-compute role: row pr, j-block jb (8 j's)
  const int hf = t >> 2, hs = t & 3;    // hT staging role: feature hf, stripe hs

  // 136-short row stride: 272B (16B aligned), S/4 = 17 (odd) => conflict-free b128
  __shared__ unsigned short Plds[16][136];
  __shared__ unsigned short Hlds[64][136];
  __shared__ float l_sm[16];

  const float S = *Sp;
  const float ssrc = s_src[i0 + pr];
  float mr = ssrc + S;
  mr = mr > 0.f ? mr : kAlpha * mr;     // valid upper bound on row scores

  float l_acc = 0.f;
  f32x4 acc = {0.f, 0.f, 0.f, 0.f};

  const size_t adj_off = (size_t)(i0 + pr) * kN + (size_t)jb * 8;
  const size_t hT_off  = (size_t)hf * kN + (size_t)hs * 32;

  int4 A0, A1; float4 d0, d1; uint4 hv0, hv1, hv2, hv3;
  auto load_chunk = [&](int c) {
    const int j0 = c * 128;
    const int4* ap = (const int4*)(adj + adj_off + j0);
    A0 = ap[0]; A1 = ap[1];
    const float* dp = s_dst + j0 + jb * 8;
    d0 = *(const float4*)dp;
    d1 = *(const float4*)(dp + 4);
    const uint4* hp = (const uint4*)(hTg + hT_off + (size_t)j0);
    hv0 = hp[0]; hv1 = hp[1]; hv2 = hp[2]; hv3 = hp[3];
  };
  load_chunk(0);

  const int mrow = lane & 15, quad = lane >> 4;
  for (int c = 0; c < kN / 128; ++c) {
    // ---- P tile: 8 scores per thread (row pr, j = c*128 + jb*8 .. +7) ----
    float pv[8];
    {
      const int* aa = (const int*)&A0;
      const float* dd = (const float*)&d0;
#pragma unroll
      for (int j = 0; j < 4; ++j) {
        float x = ssrc + dd[j];
        float e = x > 0.f ? x : kAlpha * x;
        pv[j] = aa[j] > 0 ? __expf(e - mr) : 0.f;
      }
      aa = (const int*)&A1; dd = (const float*)&d1;
#pragma unroll
      for (int j = 0; j < 4; ++j) {
        float x = ssrc + dd[j];
        float e = x > 0.f ? x : kAlpha * x;
        pv[4 + j] = aa[j] > 0 ? __expf(e - mr) : 0.f;
      }
    }
    bf16x8 ps;
#pragma unroll
    for (int j = 0; j < 8; ++j) {
      l_acc += pv[j];
      ps[j] = (short)f2bf(pv[j]);
    }
    *(bf16x8*)&Plds[pr][jb * 8] = ps;
    *(uint4*)&Hlds[hf][hs * 32 + 0]  = hv0;
    *(uint4*)&Hlds[hf][hs * 32 + 8]  = hv1;
    *(uint4*)&Hlds[hf][hs * 32 + 16] = hv2;
    *(uint4*)&Hlds[hf][hs * 32 + 24] = hv3;
    __syncthreads();

    // prefetch next chunk while MFMA runs
    if (c + 1 < kN / 128) load_chunk(c + 1);

#pragma unroll
    for (int ks = 0; ks < 4; ++ks) {
      bf16x8 av = *(const bf16x8*)&Plds[mrow][ks * 32 + quad * 8];
      bf16x8 bv = *(const bf16x8*)&Hlds[wv * 16 + mrow][ks * 32 + quad * 8];
      acc = __builtin_amdgcn_mfma_f32_16x16x32_bf16(av, bv, acc, 0, 0, 0);
    }
    __syncthreads();
  }

  // ---- l reduction: 16 consecutive lanes share a row ----
  float lv = l_acc;
  lv += __shfl_xor(lv, 8, 64);
  lv += __shfl_xor(lv, 4, 64);
  lv += __shfl_xor(lv, 2, 64);
  lv += __shfl_xor(lv, 1, 64);
  if (jb == 0) l_sm[pr] = lv;
  __syncthreads();

  // ---- epilogue: D[row=quad*4+reg][col=lane&15] ----
#pragma unroll
  for (int reg = 0; reg < 4; ++reg) {
    const int r = quad * 4 + reg;
    float v = acc[reg] / l_sm[r];
    v = v > 0.f ? v : __expf(v) - 1.f;   // elu
    out[(size_t)(i0 + r) * kFout + wv * 16 + mrow] = v;
  }
}

extern "C" void kernel_launch(void* const* d_in, const int* in_sizes, int n_in,
                              void* d_out, int out_size, void* d_ws, size_t ws_size,
                              hipStream_t stream) {
  const float* X   = (const float*)d_in[0];   // [8192][512]
  const int*   adj = (const int*)d_in[1];     // [8192][8192]
  const float* W   = (const float*)d_in[2];   // [512][64]
  const float* A   = (const float*)d_in[3];   // [128]
  float* out = (float*)d_out;                 // [8192][64] fp32

  // workspace layout (~1.07 MB)
  unsigned short* hT = (unsigned short*)d_ws;                     // 64*8192*2 = 1 MB
  float* s_src = (float*)((char*)d_ws + (size_t)kFout * kN * 2);
  float* s_dst = s_src + kN;
  float* Sp    = s_dst + kN;

  k_linear<<<kN / 16, 256, 0, stream>>>(X, W, A, hT, s_src, s_dst);
  k_smax<<<1, 1024, 0, stream>>>(s_dst, Sp);
  k_attn<<<kN / 16, 256, 0, stream>>>(adj, hT, s_src, s_dst, Sp, out);
}